// Round 1
// baseline (3673.753 us; speedup 1.0000x reference)
//
#include <hip/hip_runtime.h>
#include <math.h>

// ---------------------------------------------------------------------------
// SovereignLeviathanV2: emb -> toroidal scan -> top2 MoE -> head
// Round 1: all-fp32 correctness-first baseline.
//   K1 embed gather
//   K2 gemm<PHI>: X@phi_w+b -> tanh*pi -> tesla_gate -> store cos,sin
//      gemm<AMP>: X@amp_w+b -> sigmoid -> store sig
//   K3 sequential scan over T (2048 chains, coalesced)
//   K4 gate GEMM + softmax + top2 (8 lanes/token)
//   K5 zero moe accumulator
//   K6 build per-expert token lists (1 block, wave-aggregated LDS atomics)
//   K7 fused FFN per (expert, 32-token tile): gelu(X@w1+b1)@w2+b2, atomicAdd
//   K8 gemm<HEAD>: moe@head_w+head_b -> d_out logits
// ---------------------------------------------------------------------------

#define NTOK 8192
#define PI_F 3.14159265358979323846f
#define HARM_F 1.04719755119659774615f
#define TOL_F 0.15f

__device__ __forceinline__ float gelu_tanh(float x) {
  float x3 = x * x * x;
  return 0.5f * x * (1.f + tanhf(0.79788456080286535588f * (x + 0.044715f * x3)));
}

// K1: X[n][c] = emb[seq[n]][c]; 4096 blocks x 256, one float4 each
__global__ void k_embed(const int* __restrict__ seq, const float* __restrict__ emb,
                        float* __restrict__ X) {
  int i = blockIdx.x * 256 + threadIdx.x;      // 0 .. 8192*128-1
  int n = i >> 7, c4 = i & 127;
  int tok = seq[n];
  ((float4*)X)[(size_t)n * 128 + c4] = ((const float4*)emb)[(size_t)tok * 128 + c4];
}

__global__ void k_zero(float* __restrict__ p) {
  size_t i = (size_t)blockIdx.x * 256 + threadIdx.x;
  ((float4*)p)[i] = make_float4(0.f, 0.f, 0.f, 0.f);
}

// K2/K8: 64x64 tile GEMM, K=512 fixed, A[M,512] row-major, B[512,N] row-major.
// EPI 0: phi -> out=cos(angle), out2=sin(angle); 1: amp -> out=sigmoid; 2: head raw
template <int EPI>
__global__ __launch_bounds__(256) void k_gemm(const float* __restrict__ A,
                                              const float* __restrict__ B,
                                              const float* __restrict__ bias,
                                              float* __restrict__ out,
                                              float* __restrict__ out2, int N) {
  __shared__ float As[64 * 20];   // [m][k16 + pad4]
  __shared__ float Bs[16 * 68];   // [k][n64 + pad4]
  int tid = threadIdx.x;
  int bm = blockIdx.x * 64, bn = blockIdx.y * 64;
  int tx = tid & 15, ty = tid >> 4;
  float acc[4][4] = {};
  for (int ks = 0; ks < 32; ++ks) {
    __syncthreads();
    {
      int m = tid >> 2, kq = tid & 3;
      float4 av = *(const float4*)(A + (size_t)(bm + m) * 512 + ks * 16 + kq * 4);
      *(float4*)(&As[m * 20 + kq * 4]) = av;
      int kk = tid >> 4, n4 = tid & 15;
      float4 bv = *(const float4*)(B + (size_t)(ks * 16 + kk) * N + bn + n4 * 4);
      *(float4*)(&Bs[kk * 68 + n4 * 4]) = bv;
    }
    __syncthreads();
#pragma unroll
    for (int k4 = 0; k4 < 4; ++k4) {
      float4 a0 = *(const float4*)(&As[(ty) * 20 + k4 * 4]);
      float4 a1 = *(const float4*)(&As[(ty + 16) * 20 + k4 * 4]);
      float4 a2 = *(const float4*)(&As[(ty + 32) * 20 + k4 * 4]);
      float4 a3 = *(const float4*)(&As[(ty + 48) * 20 + k4 * 4]);
      float ar[4][4] = {{a0.x, a0.y, a0.z, a0.w},
                        {a1.x, a1.y, a1.z, a1.w},
                        {a2.x, a2.y, a2.z, a2.w},
                        {a3.x, a3.y, a3.z, a3.w}};
#pragma unroll
      for (int kk = 0; kk < 4; ++kk) {
        float4 b = *(const float4*)(&Bs[(k4 * 4 + kk) * 68 + tx * 4]);
        float br[4] = {b.x, b.y, b.z, b.w};
#pragma unroll
        for (int r = 0; r < 4; ++r)
#pragma unroll
          for (int cc = 0; cc < 4; ++cc) acc[r][cc] += ar[r][kk] * br[cc];
      }
    }
  }
#pragma unroll
  for (int r = 0; r < 4; ++r) {
    int row = bm + ty + r * 16;
#pragma unroll
    for (int cc = 0; cc < 4; ++cc) {
      int col = bn + tx * 4 + cc;
      float z = acc[r][cc] + bias[col];
      if (EPI == 0) {
        float a = tanhf(z) * PI_F;
        float nr = rintf(a / HARM_F) * HARM_F;
        if (fabsf(a - nr) < TOL_F) a = nr;
        float s, co;
        sincosf(a, &s, &co);
        out[(size_t)row * 512 + col] = co;
        out2[(size_t)row * 512 + col] = s;
      } else if (EPI == 1) {
        out[(size_t)row * 512 + col] = 1.f / (1.f + expf(-z));
      } else {
        out[(size_t)row * 256 + col] = z;
      }
    }
  }
}

// K3: sequential toroidal scan. 2048 threads, one per (b,c) chain, coalesced.
__global__ void k_scan(const float* __restrict__ cosb, const float* __restrict__ sinb,
                       const float* __restrict__ sigb, float* __restrict__ xmoe,
                       float* __restrict__ nstate) {
  int gid = blockIdx.x * 256 + threadIdx.x;  // 0..2047
  int b = gid >> 9, c = gid & 511;
  size_t base = ((size_t)b * 2048) * 512 + c;
  float state = 0.f;
  float pc[4], ps[4], pg[4];
#pragma unroll
  for (int j = 0; j < 4; ++j) {
    size_t o = base + (size_t)j * 512;
    pc[j] = cosb[o]; ps[j] = sinb[o]; pg[j] = sigb[o];
  }
  for (int tb = 0; tb < 512; ++tb) {
    int nb = (tb + 1 < 512) ? tb + 1 : 511;
    size_t offn = base + (size_t)nb * 2048;
    float nc[4], nss[4], ng[4];
#pragma unroll
    for (int j = 0; j < 4; ++j) {
      size_t o = offn + (size_t)j * 512;
      nc[j] = cosb[o]; nss[j] = sinb[o]; ng[j] = sigb[o];
    }
    size_t off = base + (size_t)tb * 2048;
#pragma unroll
    for (int j = 0; j < 4; ++j) {
      // cos*s - sin*(1-s) = fma(cos, s, fma(sin, s, -sin))
      float st = fmaf(ps[j], state, -ps[j]);
      st = fmaf(pc[j], state, st);
      st = fminf(1.f, fmaxf(-1.f, st));
      state = st;
      xmoe[off + (size_t)j * 512] = pg[j] * st;
    }
#pragma unroll
    for (int j = 0; j < 4; ++j) { pc[j] = nc[j]; ps[j] = nss[j]; pg[j] = ng[j]; }
  }
  nstate[gid] = state;
}

// K4: gate logits + softmax + top2. 8 lanes per token, 32 tokens per block.
__global__ __launch_bounds__(256) void k_gate(const float* __restrict__ xmoe,
                                              const float* __restrict__ gw_g,
                                              const float* __restrict__ gb,
                                              int* __restrict__ e01,
                                              float* __restrict__ w01) {
  __shared__ float gw[4096];
  int tid = threadIdx.x;
  for (int i = tid; i < 4096; i += 256) gw[i] = gw_g[i];
  __syncthreads();
  int tok = blockIdx.x * 32 + (tid >> 3);
  int e = tid & 7;
  float acc = gb[e];
  const float4* xr = (const float4*)(xmoe + (size_t)tok * 512);
  for (int k4 = 0; k4 < 128; ++k4) {
    float4 x = xr[k4];
    acc += x.x * gw[(k4 * 4 + 0) * 8 + e];
    acc += x.y * gw[(k4 * 4 + 1) * 8 + e];
    acc += x.z * gw[(k4 * 4 + 2) * 8 + e];
    acc += x.w * gw[(k4 * 4 + 3) * 8 + e];
  }
  // softmax over the 8-lane group
  float m = acc;
  m = fmaxf(m, __shfl_xor(m, 1));
  m = fmaxf(m, __shfl_xor(m, 2));
  m = fmaxf(m, __shfl_xor(m, 4));
  float p = expf(acc - m);
  float ss = p;
  ss += __shfl_xor(ss, 1); ss += __shfl_xor(ss, 2); ss += __shfl_xor(ss, 4);
  p /= ss;
  // top1 (ties -> lower index, matching lax.top_k)
  float v1 = p; int i1 = e;
  {
    float ov; int oi;
    ov = __shfl_xor(v1, 1); oi = __shfl_xor(i1, 1);
    if (ov > v1 || (ov == v1 && oi < i1)) { v1 = ov; i1 = oi; }
    ov = __shfl_xor(v1, 2); oi = __shfl_xor(i1, 2);
    if (ov > v1 || (ov == v1 && oi < i1)) { v1 = ov; i1 = oi; }
    ov = __shfl_xor(v1, 4); oi = __shfl_xor(i1, 4);
    if (ov > v1 || (ov == v1 && oi < i1)) { v1 = ov; i1 = oi; }
  }
  float v2 = (e == i1) ? -1.f : p; int i2 = e;
  {
    float ov; int oi;
    ov = __shfl_xor(v2, 1); oi = __shfl_xor(i2, 1);
    if (ov > v2 || (ov == v2 && oi < i2)) { v2 = ov; i2 = oi; }
    ov = __shfl_xor(v2, 2); oi = __shfl_xor(i2, 2);
    if (ov > v2 || (ov == v2 && oi < i2)) { v2 = ov; i2 = oi; }
    ov = __shfl_xor(v2, 4); oi = __shfl_xor(i2, 4);
    if (ov > v2 || (ov == v2 && oi < i2)) { v2 = ov; i2 = oi; }
  }
  if (e == 0) {
    float s2 = v1 + v2;
    e01[tok * 2] = i1;  e01[tok * 2 + 1] = i2;
    w01[tok * 2] = v1 / s2;  w01[tok * 2 + 1] = v2 / s2;
  }
}

// K6: build per-expert token lists. One block; wave-aggregated LDS atomics.
__global__ void k_build(const int* __restrict__ e01, const float* __restrict__ w01,
                        int* __restrict__ list, float* __restrict__ wlist,
                        int* __restrict__ counts) {
  __shared__ int cnt[8];
  int tid = threadIdx.x;
  if (tid < 8) cnt[tid] = 0;
  __syncthreads();
  int lane = tid & 63;
  for (int i = tid; i < 16384; i += 256) {
    int ee = e01[i];
    float w = w01[i];
    int tok = i >> 1;
    int pos = 0;
#pragma unroll
    for (int x = 0; x < 8; ++x) {
      unsigned long long mask = __ballot(ee == x);
      if (mask == 0ull) continue;
      int leader = __ffsll(mask) - 1;
      int basex = 0;
      if (lane == leader) basex = atomicAdd(&cnt[x], __popcll(mask));
      basex = __shfl(basex, leader);
      if (ee == x) pos = basex + __popcll(mask & ((1ull << lane) - 1ull));
    }
    list[ee * 8192 + pos] = tok;
    wlist[ee * 8192 + pos] = w;
  }
  __syncthreads();
  if (tid < 8) counts[tid] = cnt[tid];
}

// K7: fused FFN, one block per (expert, 32-token tile).
// z = Xs(32x512) @ w1[e][:,f:f+64]; h = gelu(z+b1); Y(32x512) += h @ w2[e][f:f+64,:]
__global__ __launch_bounds__(256) void k_ffn(
    const float* __restrict__ xmoe, const int* __restrict__ list,
    const float* __restrict__ wlist, const int* __restrict__ counts,
    const float* __restrict__ w1, const float* __restrict__ b1,
    const float* __restrict__ w2, const float* __restrict__ b2,
    float* __restrict__ moe) {
  int e = blockIdx.y;
  int cnt = counts[e];
  int tile = blockIdx.x;
  if (tile * 32 >= cnt) return;
  __shared__ float Xs[32 * 516];   // 64.5 KB, pad 4 -> conflict-free column reads
  __shared__ float Bs[16 * 68];    // w1 k-tile
  __shared__ float Hs[32 * 68];    // gelu output tile
  __shared__ float W2s[8 * 512];   // w2 kf-chunk
  __shared__ int toks[32];
  __shared__ float wts[32];
  int tid = threadIdx.x;
  if (tid < 32) {
    int idx = tile * 32 + tid;
    bool v = idx < cnt;
    toks[tid] = v ? list[e * 8192 + idx] : 0;
    wts[tid] = v ? wlist[e * 8192 + idx] : 0.f;
  }
  __syncthreads();
  for (int i = tid; i < 32 * 128; i += 256) {
    int m = i >> 7, c4 = i & 127;
    *(float4*)(&Xs[m * 516 + c4 * 4]) =
        *(const float4*)(xmoe + (size_t)toks[m] * 512 + c4 * 4);
  }
  int tx = tid & 15, ty = tid >> 4;    // GEMM1: rows {ty, ty+16}, cols tx*4..+3
  int cy = tid & 63, ry = tid >> 6;    // GEMM2: rows ry*8..+7, cols cy*8..+7
  float Y[8][8];
#pragma unroll
  for (int rr = 0; rr < 8; ++rr)
#pragma unroll
    for (int cc = 0; cc < 8; ++cc) Y[rr][cc] = b2[e * 512 + cy * 8 + cc];
  __syncthreads();  // Xs ready
  const size_t w1base = (size_t)e * 512 * 2048;
  const size_t w2base = (size_t)e * 2048 * 512;
  for (int ft = 0; ft < 32; ++ft) {
    float z[2][4] = {};
    for (int ks = 0; ks < 32; ++ks) {
      __syncthreads();
      {
        int kk = tid >> 4, j4 = tid & 15;
        *(float4*)(&Bs[kk * 68 + j4 * 4]) =
            *(const float4*)(w1 + w1base + (size_t)(ks * 16 + kk) * 2048 + ft * 64 + j4 * 4);
      }
      __syncthreads();
#pragma unroll
      for (int k4 = 0; k4 < 4; ++k4) {
        float4 a0 = *(const float4*)(&Xs[ty * 516 + ks * 16 + k4 * 4]);
        float4 a1 = *(const float4*)(&Xs[(ty + 16) * 516 + ks * 16 + k4 * 4]);
        float a0r[4] = {a0.x, a0.y, a0.z, a0.w};
        float a1r[4] = {a1.x, a1.y, a1.z, a1.w};
#pragma unroll
        for (int kk = 0; kk < 4; ++kk) {
          float4 b = *(const float4*)(&Bs[(k4 * 4 + kk) * 68 + tx * 4]);
          z[0][0] += a0r[kk] * b.x; z[0][1] += a0r[kk] * b.y;
          z[0][2] += a0r[kk] * b.z; z[0][3] += a0r[kk] * b.w;
          z[1][0] += a1r[kk] * b.x; z[1][1] += a1r[kk] * b.y;
          z[1][2] += a1r[kk] * b.z; z[1][3] += a1r[kk] * b.w;
        }
      }
    }
#pragma unroll
    for (int r = 0; r < 2; ++r)
#pragma unroll
      for (int cc = 0; cc < 4; ++cc) {
        float v = z[r][cc] + b1[e * 2048 + ft * 64 + tx * 4 + cc];
        Hs[(ty + r * 16) * 68 + tx * 4 + cc] = gelu_tanh(v);
      }
    __syncthreads();
    for (int kfs = 0; kfs < 8; ++kfs) {
      __syncthreads();  // previous chunk's W2s reads complete
#pragma unroll
      for (int s = 0; s < 4; ++s) {
        int i = tid + s * 256;
        int kf = i >> 7, c4 = i & 127;
        *(float4*)(&W2s[kf * 512 + c4 * 4]) =
            *(const float4*)(w2 + w2base + (size_t)(ft * 64 + kfs * 8 + kf) * 512 + c4 * 4);
      }
      __syncthreads();
#pragma unroll
      for (int kf = 0; kf < 8; ++kf) {
        float hv[8];
#pragma unroll
        for (int rr = 0; rr < 8; ++rr) hv[rr] = Hs[(ry * 8 + rr) * 68 + kfs * 8 + kf];
        float4 wa = *(const float4*)(&W2s[kf * 512 + cy * 8]);
        float4 wb = *(const float4*)(&W2s[kf * 512 + cy * 8 + 4]);
        float wr[8] = {wa.x, wa.y, wa.z, wa.w, wb.x, wb.y, wb.z, wb.w};
#pragma unroll
        for (int rr = 0; rr < 8; ++rr)
#pragma unroll
          for (int cc = 0; cc < 8; ++cc) Y[rr][cc] += hv[rr] * wr[cc];
      }
    }
  }
#pragma unroll
  for (int rr = 0; rr < 8; ++rr) {
    int row = ry * 8 + rr;
    float w = wts[row];
    if (w != 0.f) {
      int tok = toks[row];
      float* dst = moe + (size_t)tok * 512 + cy * 8;
#pragma unroll
      for (int cc = 0; cc < 8; ++cc) atomicAdd(dst + cc, w * Y[rr][cc]);
    }
  }
}

extern "C" void kernel_launch(void* const* d_in, const int* in_sizes, int n_in,
                              void* d_out, int out_size, void* d_ws, size_t ws_size,
                              hipStream_t stream) {
  (void)in_sizes; (void)n_in; (void)out_size; (void)ws_size;
  const int* seq     = (const int*)d_in[0];
  const float* emb   = (const float*)d_in[1];
  const float* phi_w = (const float*)d_in[2];
  const float* phi_b = (const float*)d_in[3];
  const float* amp_w = (const float*)d_in[4];
  const float* amp_b = (const float*)d_in[5];
  const float* gate_w = (const float*)d_in[6];
  const float* gate_b = (const float*)d_in[7];
  const float* w1 = (const float*)d_in[8];
  const float* b1 = (const float*)d_in[9];
  const float* w2 = (const float*)d_in[10];
  const float* b2 = (const float*)d_in[11];
  const float* head_w = (const float*)d_in[12];
  const float* head_b = (const float*)d_in[13];
  float* out = (float*)d_out;

  char* ws = (char*)d_ws;
  const size_t BUF = 16777216;  // 8192*512 fp32
  float* X    = (float*)(ws);             // X, then xmoe (in place)
  float* COSb = (float*)(ws + BUF);       // cos(angle), then moe accumulator
  float* SINb = (float*)(ws + 2 * BUF);
  float* SIGb = (float*)(ws + 3 * BUF);
  int*   list  = (int*)(ws + 4 * BUF);                    // 8*8192 ints
  float* wlist = (float*)(ws + 4 * BUF + 262144);
  int*   counts = (int*)(ws + 4 * BUF + 524288);
  int*   e01 = (int*)(ws + 4 * BUF + 524288 + 256);       // 16384 ints
  float* w01 = (float*)(ws + 4 * BUF + 524288 + 256 + 65536);
  float* MOE = COSb;
  float* XM = X;

  k_embed<<<4096, 256, 0, stream>>>(seq, emb, X);
  k_gemm<0><<<dim3(128, 8), 256, 0, stream>>>(X, phi_w, phi_b, COSb, SINb, 512);
  k_gemm<1><<<dim3(128, 8), 256, 0, stream>>>(X, amp_w, amp_b, SIGb, nullptr, 512);
  k_scan<<<8, 256, 0, stream>>>(COSb, SINb, SIGb, XM, out + 2097152);
  k_gate<<<256, 256, 0, stream>>>(XM, gate_w, gate_b, e01, w01);
  k_zero<<<4096, 256, 0, stream>>>(MOE);
  k_build<<<1, 256, 0, stream>>>(e01, w01, list, wlist, counts);
  k_ffn<<<dim3(256, 8), 256, 0, stream>>>(XM, list, wlist, counts, w1, b1, w2, b2, MOE);
  k_gemm<2><<<dim3(128, 4), 256, 0, stream>>>(MOE, head_w, head_b, out, nullptr, 256);
}

// Round 2
// 860.835 us; speedup vs baseline: 4.2677x; 4.2677x over previous
//
#include <hip/hip_runtime.h>
#include <math.h>

// ---------------------------------------------------------------------------
// SovereignLeviathanV2: emb -> toroidal scan -> top2 MoE -> head
// Round 2: MoE FFN moved to bf16 MFMA (16x16x32), weights pre-transposed to
// bf16 with bank-swizzle baked into the global layout; global_load_lds
// staging. Everything else (phi path fp32 for tesla_gate fidelity) unchanged.
// ---------------------------------------------------------------------------

#define NTOK 8192
#define PI_F 3.14159265358979323846f
#define HARM_F 1.04719755119659774615f
#define TOL_F 0.15f

typedef float f32x4 __attribute__((ext_vector_type(4)));
typedef __bf16 bf16x8 __attribute__((ext_vector_type(8)));
typedef unsigned int u32x4 __attribute__((ext_vector_type(4)));
typedef unsigned int u32x2 __attribute__((ext_vector_type(2)));

__device__ __forceinline__ float gelu_tanh(float x) {
  float x3 = x * x * x;
  return 0.5f * x * (1.f + tanhf(0.79788456080286535588f * (x + 0.044715f * x3)));
}

__device__ __forceinline__ unsigned short f2bf(float x) {
  unsigned u = __float_as_uint(x);
  unsigned r = (u + 0x7FFFu + ((u >> 16) & 1u)) >> 16;
  return (unsigned short)r;
}

__device__ __forceinline__ bf16x8 ld_frag(const void* p) {
  u32x4 v = *(const u32x4*)p;
  return __builtin_bit_cast(bf16x8, v);
}

__device__ __forceinline__ void gload16(const void* g, void* l) {
  __builtin_amdgcn_global_load_lds((const __attribute__((address_space(1))) unsigned int*)g,
                                   (__attribute__((address_space(3))) unsigned int*)l,
                                   16, 0, 0);
}

// K1: X[n][c] = emb[seq[n]][c]
__global__ void k_embed(const int* __restrict__ seq, const float* __restrict__ emb,
                        float* __restrict__ X) {
  int i = blockIdx.x * 256 + threadIdx.x;
  int n = i >> 7, c4 = i & 127;
  int tok = seq[n];
  ((float4*)X)[(size_t)n * 128 + c4] = ((const float4*)emb)[(size_t)tok * 128 + c4];
}

__global__ void k_zero(float* __restrict__ p) {
  size_t i = (size_t)blockIdx.x * 256 + threadIdx.x;
  ((float4*)p)[i] = make_float4(0.f, 0.f, 0.f, 0.f);
}

// K2/K8: fp32 64x64 tile GEMM, K=512. EPI 0: phi->cos/sin(tesla_gate); 1: amp->sigmoid; 2: head
template <int EPI>
__global__ __launch_bounds__(256) void k_gemm(const float* __restrict__ A,
                                              const float* __restrict__ B,
                                              const float* __restrict__ bias,
                                              float* __restrict__ out,
                                              float* __restrict__ out2, int N) {
  __shared__ float As[64 * 20];
  __shared__ float Bs[16 * 68];
  int tid = threadIdx.x;
  int bm = blockIdx.x * 64, bn = blockIdx.y * 64;
  int tx = tid & 15, ty = tid >> 4;
  float acc[4][4] = {};
  for (int ks = 0; ks < 32; ++ks) {
    __syncthreads();
    {
      int m = tid >> 2, kq = tid & 3;
      float4 av = *(const float4*)(A + (size_t)(bm + m) * 512 + ks * 16 + kq * 4);
      *(float4*)(&As[m * 20 + kq * 4]) = av;
      int kk = tid >> 4, n4 = tid & 15;
      float4 bv = *(const float4*)(B + (size_t)(ks * 16 + kk) * N + bn + n4 * 4);
      *(float4*)(&Bs[kk * 68 + n4 * 4]) = bv;
    }
    __syncthreads();
#pragma unroll
    for (int k4 = 0; k4 < 4; ++k4) {
      float4 a0 = *(const float4*)(&As[(ty) * 20 + k4 * 4]);
      float4 a1 = *(const float4*)(&As[(ty + 16) * 20 + k4 * 4]);
      float4 a2 = *(const float4*)(&As[(ty + 32) * 20 + k4 * 4]);
      float4 a3 = *(const float4*)(&As[(ty + 48) * 20 + k4 * 4]);
      float ar[4][4] = {{a0.x, a0.y, a0.z, a0.w},
                       {a1.x, a1.y, a1.z, a1.w},
                       {a2.x, a2.y, a2.z, a2.w},
                       {a3.x, a3.y, a3.z, a3.w}};
#pragma unroll
      for (int kk = 0; kk < 4; ++kk) {
        float4 b = *(const float4*)(&Bs[(k4 * 4 + kk) * 68 + tx * 4]);
        float br[4] = {b.x, b.y, b.z, b.w};
#pragma unroll
        for (int r = 0; r < 4; ++r)
#pragma unroll
          for (int cc = 0; cc < 4; ++cc) acc[r][cc] += ar[r][kk] * br[cc];
      }
    }
  }
#pragma unroll
  for (int r = 0; r < 4; ++r) {
    int row = bm + ty + r * 16;
#pragma unroll
    for (int cc = 0; cc < 4; ++cc) {
      int col = bn + tx * 4 + cc;
      float z = acc[r][cc] + bias[col];
      if (EPI == 0) {
        float a = tanhf(z) * PI_F;
        float nr = rintf(a / HARM_F) * HARM_F;
        if (fabsf(a - nr) < TOL_F) a = nr;
        float s, co;
        sincosf(a, &s, &co);
        out[(size_t)row * 512 + col] = co;
        out2[(size_t)row * 512 + col] = s;
      } else if (EPI == 1) {
        out[(size_t)row * 512 + col] = 1.f / (1.f + expf(-z));
      } else {
        out[(size_t)row * 256 + col] = z;
      }
    }
  }
}

// K3: sequential toroidal scan
__global__ void k_scan(const float* __restrict__ cosb, const float* __restrict__ sinb,
                       const float* __restrict__ sigb, float* __restrict__ xmoe,
                       float* __restrict__ nstate) {
  int gid = blockIdx.x * 256 + threadIdx.x;
  int b = gid >> 9, c = gid & 511;
  size_t base = ((size_t)b * 2048) * 512 + c;
  float state = 0.f;
  for (int t = 0; t < 2048; ++t) {
    size_t off = base + (size_t)t * 512;
    float pc = cosb[off], ps = sinb[off], pg = sigb[off];
    float st = fmaf(ps, state, -ps);
    st = fmaf(pc, state, st);
    st = fminf(1.f, fmaxf(-1.f, st));
    state = st;
    xmoe[off] = pg * st;
  }
  nstate[gid] = state;
}

// K4: gate logits + softmax + top2
__global__ __launch_bounds__(256) void k_gate(const float* __restrict__ xmoe,
                                              const float* __restrict__ gw_g,
                                              const float* __restrict__ gb,
                                              int* __restrict__ e01,
                                              float* __restrict__ w01) {
  __shared__ float gw[4096];
  int tid = threadIdx.x;
  for (int i = tid; i < 4096; i += 256) gw[i] = gw_g[i];
  __syncthreads();
  int tok = blockIdx.x * 32 + (tid >> 3);
  int e = tid & 7;
  float acc = gb[e];
  const float4* xr = (const float4*)(xmoe + (size_t)tok * 512);
  for (int k4 = 0; k4 < 128; ++k4) {
    float4 x = xr[k4];
    acc += x.x * gw[(k4 * 4 + 0) * 8 + e];
    acc += x.y * gw[(k4 * 4 + 1) * 8 + e];
    acc += x.z * gw[(k4 * 4 + 2) * 8 + e];
    acc += x.w * gw[(k4 * 4 + 3) * 8 + e];
  }
  float m = acc;
  m = fmaxf(m, __shfl_xor(m, 1));
  m = fmaxf(m, __shfl_xor(m, 2));
  m = fmaxf(m, __shfl_xor(m, 4));
  float p = expf(acc - m);
  float ss = p;
  ss += __shfl_xor(ss, 1); ss += __shfl_xor(ss, 2); ss += __shfl_xor(ss, 4);
  p /= ss;
  float v1 = p; int i1 = e;
  {
    float ov; int oi;
    ov = __shfl_xor(v1, 1); oi = __shfl_xor(i1, 1);
    if (ov > v1 || (ov == v1 && oi < i1)) { v1 = ov; i1 = oi; }
    ov = __shfl_xor(v1, 2); oi = __shfl_xor(i1, 2);
    if (ov > v1 || (ov == v1 && oi < i1)) { v1 = ov; i1 = oi; }
    ov = __shfl_xor(v1, 4); oi = __shfl_xor(i1, 4);
    if (ov > v1 || (ov == v1 && oi < i1)) { v1 = ov; i1 = oi; }
  }
  float v2 = (e == i1) ? -1.f : p; int i2 = e;
  {
    float ov; int oi;
    ov = __shfl_xor(v2, 1); oi = __shfl_xor(i2, 1);
    if (ov > v2 || (ov == v2 && oi < i2)) { v2 = ov; i2 = oi; }
    ov = __shfl_xor(v2, 2); oi = __shfl_xor(i2, 2);
    if (ov > v2 || (ov == v2 && oi < i2)) { v2 = ov; i2 = oi; }
    ov = __shfl_xor(v2, 4); oi = __shfl_xor(i2, 4);
    if (ov > v2 || (ov == v2 && oi < i2)) { v2 = ov; i2 = oi; }
  }
  if (e == 0) {
    float s2 = v1 + v2;
    e01[tok * 2] = i1;  e01[tok * 2 + 1] = i2;
    w01[tok * 2] = v1 / s2;  w01[tok * 2 + 1] = v2 / s2;
  }
}

// K6: build per-expert token lists
__global__ void k_build(const int* __restrict__ e01, const float* __restrict__ w01,
                        int* __restrict__ list, float* __restrict__ wlist,
                        int* __restrict__ counts) {
  __shared__ int cnt[8];
  int tid = threadIdx.x;
  if (tid < 8) cnt[tid] = 0;
  __syncthreads();
  int lane = tid & 63;
  for (int i = tid; i < 16384; i += 256) {
    int ee = e01[i];
    float w = w01[i];
    int tok = i >> 1;
    int pos = 0;
#pragma unroll
    for (int x = 0; x < 8; ++x) {
      unsigned long long mask = __ballot(ee == x);
      if (mask == 0ull) continue;
      int leader = __ffsll(mask) - 1;
      int basex = 0;
      if (lane == leader) basex = atomicAdd(&cnt[x], __popcll(mask));
      basex = __shfl(basex, leader);
      if (ee == x) pos = basex + __popcll(mask & ((1ull << lane) - 1ull));
    }
    list[ee * 8192 + pos] = tok;
    wlist[ee * 8192 + pos] = w;
  }
  __syncthreads();
  if (tid < 8) counts[tid] = cnt[tid];
}

// ---------------------------------------------------------------------------
// Weight prep: transpose + bf16-convert with bank-swizzle baked into layout.
// W1P[e][f][p] = bf16(w1[e][ k = p ^ ((f&7)<<3) ][f]),   p in [0,512)
// W2P[e][it][c][p] = bf16(w2[e][ it*32 + (p ^ (((c>>1)&3)<<3)) ][c]), p in [0,32)
// ---------------------------------------------------------------------------
__global__ __launch_bounds__(256) void k_prep_w1(const float* __restrict__ w1,
                                                 unsigned short* __restrict__ W1P) {
  __shared__ float Ls[64 * 33];
  int e = blockIdx.z, k0 = blockIdx.x * 64, f0 = blockIdx.y * 32;
  int tid = threadIdx.x;
#pragma unroll
  for (int q = 0; q < 2; ++q) {
    int idx = tid + q * 256;
    int kr = idx >> 3, fc = idx & 7;
    float4 v = *(const float4*)(w1 + ((size_t)(e * 512 + k0 + kr)) * 2048 + f0 + fc * 4);
    Ls[kr * 33 + fc * 4 + 0] = v.x;
    Ls[kr * 33 + fc * 4 + 1] = v.y;
    Ls[kr * 33 + fc * 4 + 2] = v.z;
    Ls[kr * 33 + fc * 4 + 3] = v.w;
  }
  __syncthreads();
#pragma unroll
  for (int q = 0; q < 2; ++q) {
    int idx = tid + q * 256;
    int fr = idx >> 4, p4 = idx & 15;
    int f = f0 + fr;
    int swz = (f & 7) << 3;
    ushort4 o;
    o.x = f2bf(Ls[((p4 * 4 + 0) ^ swz) * 33 + fr]);
    o.y = f2bf(Ls[((p4 * 4 + 1) ^ swz) * 33 + fr]);
    o.z = f2bf(Ls[((p4 * 4 + 2) ^ swz) * 33 + fr]);
    o.w = f2bf(Ls[((p4 * 4 + 3) ^ swz) * 33 + fr]);
    *(ushort4*)(W1P + ((size_t)(e * 2048 + f)) * 512 + k0 + p4 * 4) = o;
  }
}

__global__ __launch_bounds__(256) void k_prep_w2(const float* __restrict__ w2,
                                                 unsigned short* __restrict__ W2P) {
  __shared__ float Lw[32 * 65];
  int e = blockIdx.z, c0 = blockIdx.x * 64, it = blockIdx.y;
  int tid = threadIdx.x;
#pragma unroll
  for (int q = 0; q < 2; ++q) {
    int idx = tid + q * 256;
    int fr = idx >> 4, c4 = idx & 15;
    float4 v = *(const float4*)(w2 + ((size_t)(e * 2048 + it * 32 + fr)) * 512 + c0 + c4 * 4);
    Lw[fr * 65 + c4 * 4 + 0] = v.x;
    Lw[fr * 65 + c4 * 4 + 1] = v.y;
    Lw[fr * 65 + c4 * 4 + 2] = v.z;
    Lw[fr * 65 + c4 * 4 + 3] = v.w;
  }
  __syncthreads();
#pragma unroll
  for (int q = 0; q < 2; ++q) {
    int idx = tid + q * 256;
    int cr = idx >> 3, p4 = idx & 7;
    int c = c0 + cr;
    int swz = ((c >> 1) & 3) << 3;
    ushort4 o;
    o.x = f2bf(Lw[((p4 * 4 + 0) ^ swz) * 65 + cr]);
    o.y = f2bf(Lw[((p4 * 4 + 1) ^ swz) * 65 + cr]);
    o.z = f2bf(Lw[((p4 * 4 + 2) ^ swz) * 65 + cr]);
    o.w = f2bf(Lw[((p4 * 4 + 3) ^ swz) * 65 + cr]);
    *(ushort4*)(W2P + (((size_t)(e * 64 + it)) * 512 + c) * 32 + p4 * 4) = o;
  }
}

// ---------------------------------------------------------------------------
// K7: fused bf16-MFMA FFN. Block = (expert, 64-token tile). 64 iters over F
// in 32-wide strips. GEMM1: Z^T[f][tok] = W1T-frag x X-frag; gelu -> Hs bf16;
// GEMM2: Y^T[c][tok] += W2T-frag x H-frag (fp32 acc, 128 VGPR).
// LDS: Xs 64KB | W1s 32KB | W2s 32KB | Hs 5KB (all strips via global_load_lds)
// ---------------------------------------------------------------------------
#define XS_OFF 0
#define W1_OFF 65536
#define W2_OFF 98304
#define HS_OFF 131072

__global__ __launch_bounds__(256, 1) void k_ffn(
    const float* __restrict__ xmoe, const int* __restrict__ list,
    const float* __restrict__ wlist, const int* __restrict__ counts,
    const unsigned short* __restrict__ W1P, const float* __restrict__ b1g,
    const unsigned short* __restrict__ W2P, const float* __restrict__ b2g,
    float* __restrict__ moe) {
  int e = blockIdx.y;
  int cnt = counts[e];
  int tile = blockIdx.x;
  if (tile * 64 >= cnt) return;
  __shared__ __align__(16) char smem[136192];
  __shared__ int toks[64];
  __shared__ float wts[64];
  int tid = threadIdx.x;
  int w = tid >> 6, l = tid & 63;
  int l15 = l & 15, l4 = l >> 4;
  if (tid < 64) {
    int idx = tile * 64 + tid;
    bool v = idx < cnt;
    toks[tid] = v ? list[e * 8192 + idx] : 0;
    wts[tid] = v ? wlist[e * 8192 + idx] : 0.f;
  }
  __syncthreads();
  // stage Xs: gather + fp32->bf16, XOR-swizzled rows of 1KB
#pragma unroll
  for (int s = 0; s < 16; ++s) {
    int c = tid + s * 256;
    int row = c >> 6, k8 = c & 63;
    const float* src = xmoe + (size_t)toks[row] * 512 + k8 * 8;
    float4 v0 = *(const float4*)src;
    float4 v1 = *(const float4*)(src + 4);
    u32x4 u;
    u.x = (unsigned)f2bf(v0.x) | ((unsigned)f2bf(v0.y) << 16);
    u.y = (unsigned)f2bf(v0.z) | ((unsigned)f2bf(v0.w) << 16);
    u.z = (unsigned)f2bf(v1.x) | ((unsigned)f2bf(v1.y) << 16);
    u.w = (unsigned)f2bf(v1.z) | ((unsigned)f2bf(v1.w) << 16);
    int dst = row * 1024 + ((k8 * 16) ^ ((row & 7) << 4));
    *(u32x4*)(smem + XS_OFF + dst) = u;
  }

  f32x4 acc[8][4];
#pragma unroll
  for (int cf = 0; cf < 8; ++cf)
#pragma unroll
    for (int tf = 0; tf < 4; ++tf) acc[cf][tf] = (f32x4){0.f, 0.f, 0.f, 0.f};

  int fw = w & 1, tp = w >> 1;
  int aswz = (l & 7) << 4;
  int tok0 = tp * 32 + l15, tok1 = tok0 + 16;

  for (int it = 0; it < 64; ++it) {
    // issue strip loads (prev iter's readers done at loop-bottom barrier)
    {
      const unsigned short* s1 = W1P + ((size_t)(e * 2048 + it * 32)) * 512;
      const unsigned short* s2 = W2P + ((size_t)(e * 64 + it)) * 16384;
#pragma unroll
      for (int q = 0; q < 8; ++q) {
        int j = w * 8 + q;
        gload16(s1 + j * 512 + l * 8, smem + W1_OFF + j * 1024);
        gload16(s2 + j * 512 + l * 8, smem + W2_OFF + j * 1024);
      }
    }
    __syncthreads();  // strips ready (syncthreads drains vmcnt)

    // GEMM1: this wave's f-frag fw, tok-frags tok0,tok1
    f32x4 z0 = {0.f, 0.f, 0.f, 0.f}, z1 = z0;
    int arow = fw * 16 + l15;
#pragma unroll
    for (int ks = 0; ks < 16; ++ks) {
      int kb = (ks * 32 + l4 * 8) * 2;
      bf16x8 a  = ld_frag(smem + W1_OFF + arow * 1024 + (kb ^ aswz));
      bf16x8 b0 = ld_frag(smem + XS_OFF + tok0 * 1024 + (kb ^ aswz));
      bf16x8 b1 = ld_frag(smem + XS_OFF + tok1 * 1024 + (kb ^ aswz));
      z0 = __builtin_amdgcn_mfma_f32_16x16x32_bf16(a, b0, z0, 0, 0, 0);
      z1 = __builtin_amdgcn_mfma_f32_16x16x32_bf16(a, b1, z1, 0, 0, 0);
    }
    // bias + gelu -> Hs (bf16)
    {
      float4 bv = *(const float4*)(b1g + e * 2048 + it * 32 + fw * 16 + l4 * 4);
      float g00 = gelu_tanh(z0.x + bv.x), g01 = gelu_tanh(z0.y + bv.y);
      float g02 = gelu_tanh(z0.z + bv.z), g03 = gelu_tanh(z0.w + bv.w);
      float g10 = gelu_tanh(z1.x + bv.x), g11 = gelu_tanh(z1.y + bv.y);
      float g12 = gelu_tanh(z1.z + bv.z), g13 = gelu_tanh(z1.w + bv.w);
      u32x2 p0, p1;
      p0.x = (unsigned)f2bf(g00) | ((unsigned)f2bf(g01) << 16);
      p0.y = (unsigned)f2bf(g02) | ((unsigned)f2bf(g03) << 16);
      p1.x = (unsigned)f2bf(g10) | ((unsigned)f2bf(g11) << 16);
      p1.y = (unsigned)f2bf(g12) | ((unsigned)f2bf(g13) << 16);
      int fb = (fw * 16 + l4 * 4) * 2;
      *(u32x2*)(smem + HS_OFF + tok0 * 80 + fb) = p0;
      *(u32x2*)(smem + HS_OFF + tok1 * 80 + fb) = p1;
    }
    __syncthreads();  // Hs visible

    // GEMM2: K=32 (one MFMA k-step), 8 c-frags x 4 tok-frags
    {
      bf16x8 hf[4];
#pragma unroll
      for (int tf = 0; tf < 4; ++tf)
        hf[tf] = ld_frag(smem + HS_OFF + (tf * 16 + l15) * 80 + l4 * 16);
#pragma unroll
      for (int cf = 0; cf < 8; ++cf) {
        int c = w * 128 + cf * 16 + l15;
        int swz2 = ((c >> 1) & 3) << 4;
        bf16x8 a = ld_frag(smem + W2_OFF + c * 64 + ((l4 * 16) ^ swz2));
#pragma unroll
        for (int tf = 0; tf < 4; ++tf)
          acc[cf][tf] = __builtin_amdgcn_mfma_f32_16x16x32_bf16(a, hf[tf], acc[cf][tf], 0, 0, 0);
      }
    }
    __syncthreads();  // GEMM2 reads done before next-iter strip overwrite
  }

  // epilogue: (acc + b2) * w_tok -> atomicAdd moe[tok][c]
#pragma unroll
  for (int tf = 0; tf < 4; ++tf) {
    int tloc = tf * 16 + l15;
    int tok = toks[tloc];
    float wt = wts[tloc];
    if (wt != 0.f) {
#pragma unroll
      for (int cf = 0; cf < 8; ++cf) {
        int c0 = w * 128 + cf * 16 + l4 * 4;
        float4 bv = *(const float4*)(b2g + e * 512 + c0);
        float* dst = moe + (size_t)tok * 512 + c0;
        atomicAdd(dst + 0, (acc[cf][tf].x + bv.x) * wt);
        atomicAdd(dst + 1, (acc[cf][tf].y + bv.y) * wt);
        atomicAdd(dst + 2, (acc[cf][tf].z + bv.z) * wt);
        atomicAdd(dst + 3, (acc[cf][tf].w + bv.w) * wt);
      }
    }
  }
}

extern "C" void kernel_launch(void* const* d_in, const int* in_sizes, int n_in,
                              void* d_out, int out_size, void* d_ws, size_t ws_size,
                              hipStream_t stream) {
  (void)in_sizes; (void)n_in; (void)out_size; (void)ws_size;
  const int* seq     = (const int*)d_in[0];
  const float* emb   = (const float*)d_in[1];
  const float* phi_w = (const float*)d_in[2];
  const float* phi_b = (const float*)d_in[3];
  const float* amp_w = (const float*)d_in[4];
  const float* amp_b = (const float*)d_in[5];
  const float* gate_w = (const float*)d_in[6];
  const float* gate_b = (const float*)d_in[7];
  const float* w1 = (const float*)d_in[8];
  const float* b1 = (const float*)d_in[9];
  const float* w2 = (const float*)d_in[10];
  const float* b2 = (const float*)d_in[11];
  const float* head_w = (const float*)d_in[12];
  const float* head_b = (const float*)d_in[13];
  float* out = (float*)d_out;

  char* ws = (char*)d_ws;
  const size_t BUF = 16777216;  // 8192*512 fp32
  float* X    = (float*)(ws);             // X, then xmoe (in place)
  float* COSb = (float*)(ws + BUF);       // cos(angle), then moe accumulator
  float* SINb = (float*)(ws + 2 * BUF);   // sin(angle), then W1P (bf16)
  float* SIGb = (float*)(ws + 3 * BUF);   // sigmoid,    then W2P (bf16)
  int*   list  = (int*)(ws + 4 * BUF);
  float* wlist = (float*)(ws + 4 * BUF + 262144);
  int*   counts = (int*)(ws + 4 * BUF + 524288);
  int*   e01 = (int*)(ws + 4 * BUF + 524288 + 256);
  float* w01 = (float*)(ws + 4 * BUF + 524288 + 256 + 65536);
  float* MOE = COSb;
  float* XM = X;
  unsigned short* W1P = (unsigned short*)SINb;
  unsigned short* W2P = (unsigned short*)SIGb;

  k_embed<<<4096, 256, 0, stream>>>(seq, emb, X);
  k_gemm<0><<<dim3(128, 8), 256, 0, stream>>>(X, phi_w, phi_b, COSb, SINb, 512);
  k_gemm<1><<<dim3(128, 8), 256, 0, stream>>>(X, amp_w, amp_b, SIGb, nullptr, 512);
  k_scan<<<8, 256, 0, stream>>>(COSb, SINb, SIGb, XM, out + 2097152);
  k_gate<<<256, 256, 0, stream>>>(XM, gate_w, gate_b, e01, w01);
  k_prep_w1<<<dim3(8, 64, 8), 256, 0, stream>>>(w1, W1P);
  k_prep_w2<<<dim3(8, 64, 8), 256, 0, stream>>>(w2, W2P);
  k_zero<<<4096, 256, 0, stream>>>(MOE);
  k_build<<<1, 256, 0, stream>>>(e01, w01, list, wlist, counts);
  k_ffn<<<dim3(128, 8), 256, 0, stream>>>(XM, list, wlist, counts, W1P, b1, W2P, b2, MOE);
  k_gemm<2><<<dim3(128, 4), 256, 0, stream>>>(MOE, head_w, head_b, out, nullptr, 256);
}

// Round 4
// 727.877 us; speedup vs baseline: 5.0472x; 1.1827x over previous
//
#include <hip/hip_runtime.h>
#include <hip/hip_fp16.h>
#include <math.h>

// ---------------------------------------------------------------------------
// SovereignLeviathanV2  round 4 = round 3 + two fixes:
//  (1) k_ffn grid covers full 8192 tokens/expert (routing is skewed; 56 tiles
//      missed the largest expert's tail -> stale fp32-as-bf16 -> NaN).
//  (2) k_phi launch_bounds (256,2) so the 8x8 fp32 microtile doesn't spill.
// Structure:
//  - k_phi: fused fp32 GEMM (phi -> tesla-gate cos/sin; amp -> sigmoid)
//  - k_scan: 4-buffer rotating prefetch
//  - k_ffn: 8-wave 32x32x16 bf16 MFMA, F-strip 256, frag-packed weights
//    streamed global->reg; Xs+Hs swizzled LDS; writes weighted rows Yb (bf16)
//  - k_head: bf16 MFMA, A = Yb[pos1]+Yb[pos2] gather-sum
// ---------------------------------------------------------------------------

#define PI_F 3.14159265358979323846f
#define HARM_F 1.04719755119659774615f
#define INV_HARM_F 0.95492965855137201461f
#define TOL_F 0.15f

typedef float f32x16 __attribute__((ext_vector_type(16)));
typedef __bf16 bf16x8 __attribute__((ext_vector_type(8)));
typedef unsigned int u32x4 __attribute__((ext_vector_type(4)));
typedef unsigned int u32x2 __attribute__((ext_vector_type(2)));

__device__ __forceinline__ float gelu_tanh(float x) {
  float x3 = x * x * x;
  return 0.5f * x * (1.f + tanhf(0.79788456080286535588f * (x + 0.044715f * x3)));
}
__device__ __forceinline__ unsigned short f2bf(float x) {
  unsigned u = __float_as_uint(x);
  unsigned r = (u + 0x7FFFu + ((u >> 16) & 1u)) >> 16;
  return (unsigned short)r;
}
__device__ __forceinline__ float bflo(unsigned u) { return __uint_as_float(u << 16); }
__device__ __forceinline__ float bfhi(unsigned u) { return __uint_as_float(u & 0xFFFF0000u); }
__device__ __forceinline__ bf16x8 ld_frag(const void* p) {
  u32x4 v = *(const u32x4*)p;
  return __builtin_bit_cast(bf16x8, v);
}

// K1: X[n][c] = emb[seq[n]][c]
__global__ void k_embed(const int* __restrict__ seq, const float* __restrict__ emb,
                        float* __restrict__ X) {
  int i = blockIdx.x * 256 + threadIdx.x;
  int n = i >> 7, c4 = i & 127;
  int tok = seq[n];
  ((float4*)X)[(size_t)n * 128 + c4] = ((const float4*)emb)[(size_t)tok * 128 + c4];
}

// ---------------------------------------------------------------------------
// Generic B-operand frag pack: src fp32 [K][N] (row-major, leading dim ld)
// -> bf16 frag entries. Entry (nb, ksGlobal): 64 lanes x 16B, lane l holds
// src[ksGlobal*16 + (l>>5)*8 + j][nb*32 + (l&31)], j=0..7.
// grid: (nb, kseg(512-row slabs), e)
// ---------------------------------------------------------------------------
__global__ __launch_bounds__(256) void k_pack_b(const float* __restrict__ src, int ld,
                                                size_t srcE, unsigned short* __restrict__ dst,
                                                size_t dstE, int fragKtot) {
  __shared__ float Ls[512 * 33];
  int nb = blockIdx.x, kseg = blockIdx.y, e = blockIdx.z;
  const float* s = src + (size_t)e * srcE + (size_t)kseg * 512 * ld + nb * 32;
  unsigned short* d = dst + (size_t)e * dstE + ((size_t)(nb * fragKtot + kseg * 32)) * 512;
  int tid = threadIdx.x;
#pragma unroll
  for (int q = 0; q < 16; ++q) {
    int i = tid + q * 256;
    int row = i >> 3, c4 = i & 7;
    float4 v = *(const float4*)(s + (size_t)row * ld + c4 * 4);
    Ls[row * 33 + c4 * 4 + 0] = v.x;
    Ls[row * 33 + c4 * 4 + 1] = v.y;
    Ls[row * 33 + c4 * 4 + 2] = v.z;
    Ls[row * 33 + c4 * 4 + 3] = v.w;
  }
  __syncthreads();
#pragma unroll
  for (int q = 0; q < 8; ++q) {
    int i = tid + q * 256;
    int ks = i >> 6, l = i & 63;
    int col = l & 31, kb = (l >> 5) * 8 + ks * 16;
    u32x4 o;
    o.x = (unsigned)f2bf(Ls[(kb + 0) * 33 + col]) | ((unsigned)f2bf(Ls[(kb + 1) * 33 + col]) << 16);
    o.y = (unsigned)f2bf(Ls[(kb + 2) * 33 + col]) | ((unsigned)f2bf(Ls[(kb + 3) * 33 + col]) << 16);
    o.z = (unsigned)f2bf(Ls[(kb + 4) * 33 + col]) | ((unsigned)f2bf(Ls[(kb + 5) * 33 + col]) << 16);
    o.w = (unsigned)f2bf(Ls[(kb + 6) * 33 + col]) | ((unsigned)f2bf(Ls[(kb + 7) * 33 + col]) << 16);
    *(u32x4*)(d + (size_t)ks * 512 + l * 8) = o;
  }
}

// ---------------------------------------------------------------------------
// K2: fused phi+amp fp32 GEMM. M=8192, K=512, N=1024 (by<4: phi, else amp).
// 128x128 tile, BK=16, 8x8 microtile, double-buffered LDS.
// ---------------------------------------------------------------------------
__global__ __launch_bounds__(256, 2) void k_phi(const float* __restrict__ A,
                                                const float* __restrict__ phiW,
                                                const float* __restrict__ phiB,
                                                const float* __restrict__ ampW,
                                                const float* __restrict__ ampB,
                                                float* __restrict__ cosO,
                                                float* __restrict__ sinO,
                                                float* __restrict__ sigO) {
  __shared__ float As[2][16 * 132];
  __shared__ float Bs[2][16 * 132];
  int tid = threadIdx.x;
  int tx = tid & 15, ty = tid >> 4;
  int bm = blockIdx.x * 128;
  int by = blockIdx.y;
  const float* Bsrc = (by < 4) ? phiW : ampW;
  const float* bias = (by < 4) ? phiB : ampB;
  int cb = (by & 3) * 128;
  float acc[8][8];
#pragma unroll
  for (int r = 0; r < 8; ++r)
#pragma unroll
    for (int c = 0; c < 8; ++c) acc[r][c] = 0.f;

#define STAGE_PHI(BUF, KT)                                                     \
  {                                                                            \
    _Pragma("unroll") for (int s = 0; s < 2; ++s) {                            \
      int i = tid + s * 256;                                                   \
      int row = i >> 2, kq = i & 3;                                            \
      float4 v = *(const float4*)(A + (size_t)(bm + row) * 512 + (KT)*16 + kq * 4); \
      As[BUF][(kq * 4 + 0) * 132 + row] = v.x;                                 \
      As[BUF][(kq * 4 + 1) * 132 + row] = v.y;                                 \
      As[BUF][(kq * 4 + 2) * 132 + row] = v.z;                                 \
      As[BUF][(kq * 4 + 3) * 132 + row] = v.w;                                 \
    }                                                                          \
    _Pragma("unroll") for (int s = 0; s < 2; ++s) {                            \
      int i = tid + s * 256;                                                   \
      int kk = i >> 5, g = i & 31;                                             \
      float4 v = *(const float4*)(Bsrc + (size_t)((KT)*16 + kk) * 512 + cb + g * 4); \
      *(float4*)(&Bs[BUF][kk * 132 + g * 4]) = v;                              \
    }                                                                          \
  }

  STAGE_PHI(0, 0);
  for (int kt = 0; kt < 32; ++kt) {
    __syncthreads();
    if (kt + 1 < 32) {
      if ((kt & 1) == 0) STAGE_PHI(1, kt + 1) else STAGE_PHI(0, kt + 1)
    }
    const float* Ab = As[kt & 1];
    const float* Bb = Bs[kt & 1];
#pragma unroll
    for (int kk = 0; kk < 16; ++kk) {
      float4 a0 = *(const float4*)(&Ab[kk * 132 + ty * 8]);
      float4 a1 = *(const float4*)(&Ab[kk * 132 + ty * 8 + 4]);
      float4 b0 = *(const float4*)(&Bb[kk * 132 + tx * 8]);
      float4 b1 = *(const float4*)(&Bb[kk * 132 + tx * 8 + 4]);
      float ar[8] = {a0.x, a0.y, a0.z, a0.w, a1.x, a1.y, a1.z, a1.w};
      float br[8] = {b0.x, b0.y, b0.z, b0.w, b1.x, b1.y, b1.z, b1.w};
#pragma unroll
      for (int r = 0; r < 8; ++r)
#pragma unroll
        for (int c = 0; c < 8; ++c) acc[r][c] = fmaf(ar[r], br[c], acc[r][c]);
    }
  }
  // epilogue
#pragma unroll
  for (int r = 0; r < 8; ++r) {
    int m = bm + ty * 8 + r;
    float o0[8];
    if (by < 4) {
      float o1[8];
#pragma unroll
      for (int c = 0; c < 8; ++c) {
        float z = acc[r][c] + bias[cb + tx * 8 + c];
        float a = tanhf(z) * PI_F;
        float nr = rintf(a * INV_HARM_F) * HARM_F;
        if (fabsf(a - nr) < TOL_F) a = nr;
        float sn, cs;
        sincosf(a, &sn, &cs);
        o0[c] = cs;
        o1[c] = sn;
      }
      float* cp = cosO + (size_t)m * 512 + cb + tx * 8;
      float* sp = sinO + (size_t)m * 512 + cb + tx * 8;
      *(float4*)cp = make_float4(o0[0], o0[1], o0[2], o0[3]);
      *(float4*)(cp + 4) = make_float4(o0[4], o0[5], o0[6], o0[7]);
      *(float4*)sp = make_float4(o1[0], o1[1], o1[2], o1[3]);
      *(float4*)(sp + 4) = make_float4(o1[4], o1[5], o1[6], o1[7]);
    } else {
#pragma unroll
      for (int c = 0; c < 8; ++c) {
        float z = acc[r][c] + bias[cb + tx * 8 + c];
        o0[c] = 1.f / (1.f + expf(-z));
      }
      float* gp = sigO + (size_t)m * 512 + cb + tx * 8;
      *(float4*)gp = make_float4(o0[0], o0[1], o0[2], o0[3]);
      *(float4*)(gp + 4) = make_float4(o0[4], o0[5], o0[6], o0[7]);
    }
  }
}

// K3: toroidal scan, 4-buffer rotating prefetch. 32 blocks x 64 threads.
__global__ void k_scan(const float* __restrict__ cosb, const float* __restrict__ sinb,
                       const float* __restrict__ sigb, float* __restrict__ xmoe,
                       float* __restrict__ nstate) {
  int gid = blockIdx.x * 64 + threadIdx.x;  // 0..2047
  size_t b = gid >> 9, c = gid & 511;
  size_t base = (b * 2048) * 512 + c;
  float state = 0.f;
  float C0[8], S0[8], G0[8], C1[8], S1[8], G1[8];
  float C2[8], S2[8], G2[8], C3[8], S3[8], G3[8];
#define LOADB(CB, SB, GB, blk)                                                  \
  {                                                                             \
    int bb = (blk) < 255 ? (blk) : 255;                                         \
    size_t o = base + (size_t)bb * 8 * 512;                                     \
    _Pragma("unroll") for (int j = 0; j < 8; ++j) {                             \
      size_t oo = o + (size_t)j * 512;                                          \
      CB[j] = cosb[oo]; SB[j] = sinb[oo]; GB[j] = sigb[oo];                     \
    }                                                                           \
  }
#define COMPB(CB, SB, GB, blk)                                                  \
  {                                                                             \
    size_t o = base + (size_t)(blk)*8 * 512;                                    \
    _Pragma("unroll") for (int j = 0; j < 8; ++j) {                             \
      float st = fmaf(SB[j], state, -SB[j]);                                    \
      st = fmaf(CB[j], state, st);                                              \
      st = fminf(1.f, fmaxf(-1.f, st));                                         \
      state = st;                                                               \
      xmoe[o + (size_t)j * 512] = GB[j] * st;                                   \
    }                                                                           \
  }
  LOADB(C0, S0, G0, 0);
  LOADB(C1, S1, G1, 1);
  LOADB(C2, S2, G2, 2);
  for (int i = 0; i < 64; ++i) {
    LOADB(C3, S3, G3, 4 * i + 3);
    COMPB(C0, S0, G0, 4 * i);
    LOADB(C0, S0, G0, 4 * i + 4);
    COMPB(C1, S1, G1, 4 * i + 1);
    LOADB(C1, S1, G1, 4 * i + 5);
    COMPB(C2, S2, G2, 4 * i + 2);
    LOADB(C2, S2, G2, 4 * i + 6);
    COMPB(C3, S3, G3, 4 * i + 3);
  }
  nstate[gid] = state;
}

// K4: gate logits + softmax + top2 -> packed e01p/w01p
__global__ __launch_bounds__(256) void k_gate(const float* __restrict__ xmoe,
                                              const float* __restrict__ gw_g,
                                              const float* __restrict__ gb,
                                              int* __restrict__ e01p,
                                              unsigned* __restrict__ w01p) {
  __shared__ float gw[4096];
  int tid = threadIdx.x;
  for (int i = tid; i < 4096; i += 256) gw[i] = gw_g[i];
  __syncthreads();
  int tok = blockIdx.x * 32 + (tid >> 3);
  int e = tid & 7;
  float acc = gb[e];
  const float4* xr = (const float4*)(xmoe + (size_t)tok * 512);
  for (int k4 = 0; k4 < 128; ++k4) {
    float4 x = xr[k4];
    acc += x.x * gw[(k4 * 4 + 0) * 8 + e];
    acc += x.y * gw[(k4 * 4 + 1) * 8 + e];
    acc += x.z * gw[(k4 * 4 + 2) * 8 + e];
    acc += x.w * gw[(k4 * 4 + 3) * 8 + e];
  }
  float m = acc;
  m = fmaxf(m, __shfl_xor(m, 1));
  m = fmaxf(m, __shfl_xor(m, 2));
  m = fmaxf(m, __shfl_xor(m, 4));
  float p = expf(acc - m);
  float ss = p;
  ss += __shfl_xor(ss, 1); ss += __shfl_xor(ss, 2); ss += __shfl_xor(ss, 4);
  p /= ss;
  float v1 = p; int i1 = e;
  {
    float ov; int oi;
    ov = __shfl_xor(v1, 1); oi = __shfl_xor(i1, 1);
    if (ov > v1 || (ov == v1 && oi < i1)) { v1 = ov; i1 = oi; }
    ov = __shfl_xor(v1, 2); oi = __shfl_xor(i1, 2);
    if (ov > v1 || (ov == v1 && oi < i1)) { v1 = ov; i1 = oi; }
    ov = __shfl_xor(v1, 4); oi = __shfl_xor(i1, 4);
    if (ov > v1 || (ov == v1 && oi < i1)) { v1 = ov; i1 = oi; }
  }
  float v2 = (e == i1) ? -1.f : p; int i2 = e;
  {
    float ov; int oi;
    ov = __shfl_xor(v2, 1); oi = __shfl_xor(i2, 1);
    if (ov > v2 || (ov == v2 && oi < i2)) { v2 = ov; i2 = oi; }
    ov = __shfl_xor(v2, 2); oi = __shfl_xor(i2, 2);
    if (ov > v2 || (ov == v2 && oi < i2)) { v2 = ov; i2 = oi; }
    ov = __shfl_xor(v2, 4); oi = __shfl_xor(i2, 4);
    if (ov > v2 || (ov == v2 && oi < i2)) { v2 = ov; i2 = oi; }
  }
  if (e == 0) {
    float s2 = v1 + v2;
    __half h1 = __float2half(v1 / s2), h2 = __float2half(v2 / s2);
    e01p[tok] = i1 | (i2 << 8);
    w01p[tok] = (unsigned)__half_as_ushort(h1) | ((unsigned)__half_as_ushort(h2) << 16);
  }
}

// K6: counts -> eoff prefix -> scatter (list/wlist/tokpos), 1 block
__global__ void k_build(const int* __restrict__ e01p, const unsigned* __restrict__ w01p,
                        int* __restrict__ list, float* __restrict__ wlist,
                        int* __restrict__ counts, int* __restrict__ eoff,
                        int* __restrict__ tokpos) {
  __shared__ int cnt[8], cur[8];
  int tid = threadIdx.x, lane = tid & 63;
  if (tid < 8) cnt[tid] = 0;
  __syncthreads();
  for (int i = tid; i < 16384; i += 256) {
    int tok = i >> 1, j = i & 1;
    int ee = (e01p[tok] >> (8 * j)) & 255;
#pragma unroll
    for (int x = 0; x < 8; ++x) {
      unsigned long long m = __ballot(ee == x);
      if (m != 0ull && lane == (__ffsll((long long)m) - 1)) atomicAdd(&cnt[x], __popcll(m));
    }
  }
  __syncthreads();
  if (tid == 0) {
    int s = 0;
#pragma unroll
    for (int x = 0; x < 8; ++x) {
      cur[x] = s; eoff[x] = s; counts[x] = cnt[x]; s += cnt[x];
    }
  }
  __syncthreads();
  for (int i = tid; i < 16384; i += 256) {
    int tok = i >> 1, j = i & 1;
    int ee = (e01p[tok] >> (8 * j)) & 255;
    unsigned wp = w01p[tok];
    unsigned short us = (unsigned short)(j ? (wp >> 16) : (wp & 0xFFFFu));
    float w = __half2float(__ushort_as_half(us));
    int pos = 0;
#pragma unroll
    for (int x = 0; x < 8; ++x) {
      unsigned long long m = __ballot(ee == x);
      if (m == 0ull) continue;
      int leader = __ffsll((long long)m) - 1;
      int bb = 0;
      if (lane == leader) bb = atomicAdd(&cur[x], __popcll(m));
      bb = __shfl(bb, leader);
      if (ee == x) pos = bb + __popcll(m & ((1ull << lane) - 1ull));
    }
    list[pos] = tok;
    wlist[pos] = w;
    tokpos[i] = pos;
  }
}

// ---------------------------------------------------------------------------
// K7: fused MoE FFN. Block = (expert, 64-token tile), 512 thr / 8 waves.
// F-loop strips of 256 (8 iters). GEMM1: Z^T per wave (f-block w); gelu -> Hs.
// GEMM2: Y^T[c x tok] acc, wave c-block w*64. W1/W2 streamed frag-packed.
// Epilogue: (+b2)*wt -> bf16 -> LDS bounce -> Yb rows. LDS ~99KB.
// ---------------------------------------------------------------------------
#define HS_OFF 65536

__global__ __launch_bounds__(512, 2) void k_ffn(
    const float* __restrict__ xmoe, const int* __restrict__ list,
    const float* __restrict__ wlist, const int* __restrict__ counts,
    const int* __restrict__ eoff,
    const unsigned short* __restrict__ W1Pk, const float* __restrict__ b1g,
    const unsigned short* __restrict__ W2Pk, const float* __restrict__ b2g,
    unsigned short* __restrict__ Yb) {
  int e = blockIdx.y, tile = blockIdx.x;
  int cnt = counts[e];
  if (tile * 64 >= cnt) return;
  int base = eoff[e] + tile * 64;
  int valid = cnt - tile * 64;
  if (valid > 64) valid = 64;
  __shared__ __align__(16) char smem[98304];
  __shared__ int toks[64];
  __shared__ float wts[64];
  int tid = threadIdx.x;
  int w = tid >> 6, l = tid & 63;
  int l31 = l & 31, hi = l >> 5;
  int sw = (l31 & 7) << 4;
  if (tid < 64) {
    int idx = tile * 64 + tid;
    bool v = idx < cnt;
    toks[tid] = list[eoff[e] + (v ? idx : 0)];
    wts[tid] = v ? wlist[eoff[e] + idx] : 0.f;
  }
  __syncthreads();
  // stage Xs: 64 rows x 512 bf16, XOR-swizzled 16B units
#pragma unroll
  for (int s = 0; s < 8; ++s) {
    int i = tid + s * 512;
    int row = i >> 6, g = i & 63;
    const float* src = xmoe + (size_t)toks[row] * 512 + g * 8;
    float4 v0 = *(const float4*)src;
    float4 v1 = *(const float4*)(src + 4);
    u32x4 u;
    u.x = (unsigned)f2bf(v0.x) | ((unsigned)f2bf(v0.y) << 16);
    u.y = (unsigned)f2bf(v0.z) | ((unsigned)f2bf(v0.w) << 16);
    u.z = (unsigned)f2bf(v1.x) | ((unsigned)f2bf(v1.y) << 16);
    u.w = (unsigned)f2bf(v1.z) | ((unsigned)f2bf(v1.w) << 16);
    *(u32x4*)(smem + row * 1024 + ((g * 16) ^ ((row & 7) << 4))) = u;
  }
  f32x16 acc00, acc01, acc10, acc11;
#pragma unroll
  for (int i = 0; i < 16; ++i) { acc00[i] = 0.f; acc01[i] = 0.f; acc10[i] = 0.f; acc11[i] = 0.f; }
  __syncthreads();

  for (int it = 0; it < 8; ++it) {
    // ---- GEMM1: wave w = f-block (32 f of strip 256) ----
    f32x16 z0, z1;
#pragma unroll
    for (int i = 0; i < 16; ++i) { z0[i] = 0.f; z1[i] = 0.f; }
    const unsigned short* w1p =
        W1Pk + (((size_t)e * 64 + it * 8 + w) * 32) * 512 + l * 8;
#pragma unroll 8
    for (int ks = 0; ks < 32; ++ks) {
      bf16x8 a = *(const bf16x8*)(w1p + (size_t)ks * 512);
      int kb = ks * 32 + hi * 16;
      bf16x8 b0 = ld_frag(smem + l31 * 1024 + (kb ^ sw));
      bf16x8 bq = ld_frag(smem + (l31 + 32) * 1024 + (kb ^ sw));
      z0 = __builtin_amdgcn_mfma_f32_32x32x16_bf16(a, b0, z0, 0, 0, 0);
      z1 = __builtin_amdgcn_mfma_f32_32x32x16_bf16(a, bq, z1, 0, 0, 0);
    }
    // bias + gelu -> Hs (row = tok, col = f within strip)
#pragma unroll
    for (int rq = 0; rq < 4; ++rq) {
      int f0 = 8 * rq + 4 * hi;
      float4 bv = *(const float4*)(b1g + e * 2048 + it * 256 + w * 32 + f0);
      float g0 = gelu_tanh(z0[4 * rq + 0] + bv.x);
      float g1 = gelu_tanh(z0[4 * rq + 1] + bv.y);
      float g2 = gelu_tanh(z0[4 * rq + 2] + bv.z);
      float g3 = gelu_tanh(z0[4 * rq + 3] + bv.w);
      u32x2 p;
      p.x = (unsigned)f2bf(g0) | ((unsigned)f2bf(g1) << 16);
      p.y = (unsigned)f2bf(g2) | ((unsigned)f2bf(g3) << 16);
      *(u32x2*)(smem + HS_OFF + l31 * 512 + (((w * 32 + f0) * 2) ^ sw)) = p;
      g0 = gelu_tanh(z1[4 * rq + 0] + bv.x);
      g1 = gelu_tanh(z1[4 * rq + 1] + bv.y);
      g2 = gelu_tanh(z1[4 * rq + 2] + bv.z);
      g3 = gelu_tanh(z1[4 * rq + 3] + bv.w);
      p.x = (unsigned)f2bf(g0) | ((unsigned)f2bf(g1) << 16);
      p.y = (unsigned)f2bf(g2) | ((unsigned)f2bf(g3) << 16);
      *(u32x2*)(smem + HS_OFF + (l31 + 32) * 512 + (((w * 32 + f0) * 2) ^ sw)) = p;
    }
    __syncthreads();
    // ---- GEMM2: wave w = c-block (64 c), K = strip 256 ----
    const unsigned short* w2p =
        W2Pk + (((size_t)e * 16 + w * 2) * 128 + it * 16) * 512 + l * 8;
#pragma unroll 4
    for (int fs = 0; fs < 16; ++fs) {
      bf16x8 a0 = *(const bf16x8*)(w2p + (size_t)fs * 512);
      bf16x8 a1 = *(const bf16x8*)(w2p + (size_t)fs * 512 + 128 * 512);
      int fb = fs * 32 + hi * 16;
      bf16x8 h0 = ld_frag(smem + HS_OFF + l31 * 512 + (fb ^ sw));
      bf16x8 h1 = ld_frag(smem + HS_OFF + (l31 + 32) * 512 + (fb ^ sw));
      acc00 = __builtin_amdgcn_mfma_f32_32x32x16_bf16(a0, h0, acc00, 0, 0, 0);
      acc01 = __builtin_amdgcn_mfma_f32_32x32x16_bf16(a0, h1, acc01, 0, 0, 0);
      acc10 = __builtin_amdgcn_mfma_f32_32x32x16_bf16(a1, h0, acc10, 0, 0, 0);
      acc11 = __builtin_amdgcn_mfma_f32_32x32x16_bf16(a1, h1, acc11, 0, 0, 0);
    }
    __syncthreads();
  }
  // epilogue: (acc + b2) * wt -> bf16 -> LDS bounce (Xs area) [tok][c]
#pragma unroll
  for (int cf = 0; cf < 2; ++cf) {
#pragma unroll
    for (int rq = 0; rq < 4; ++rq) {
      int c0 = w * 64 + cf * 32 + 8 * rq + 4 * hi;
      float4 b2v = *(const float4*)(b2g + e * 512 + c0);
#pragma unroll
      for (int tf = 0; tf < 2; ++tf) {
        int tok = tf * 32 + l31;
        float wt = wts[tok];
        float r0, r1, r2, r3;
        if (cf == 0) {
          if (tf == 0) { r0 = acc00[4*rq+0]; r1 = acc00[4*rq+1]; r2 = acc00[4*rq+2]; r3 = acc00[4*rq+3]; }
          else          { r0 = acc01[4*rq+0]; r1 = acc01[4*rq+1]; r2 = acc01[4*rq+2]; r3 = acc01[4*rq+3]; }
        } else {
          if (tf == 0) { r0 = acc10[4*rq+0]; r1 = acc10[4*rq+1]; r2 = acc10[4*rq+2]; r3 = acc10[4*rq+3]; }
          else          { r0 = acc11[4*rq+0]; r1 = acc11[4*rq+1]; r2 = acc11[4*rq+2]; r3 = acc11[4*rq+3]; }
        }
        u32x2 p;
        p.x = (unsigned)f2bf((r0 + b2v.x) * wt) | ((unsigned)f2bf((r1 + b2v.y) * wt) << 16);
        p.y = (unsigned)f2bf((r2 + b2v.z) * wt) | ((unsigned)f2bf((r3 + b2v.w) * wt) << 16);
        *(u32x2*)(smem + tok * 1024 + ((c0 * 2) ^ ((tok & 7) << 4))) = p;
      }
    }
  }
  __syncthreads();
  // copy out rows [0, valid)
#pragma unroll
  for (int s = 0; s < 8; ++s) {
    int i = tid + s * 512;
    int row = i >> 6, g = i & 63;
    if (row < valid) {
      u32x4 v = *(u32x4*)(smem + row * 1024 + ((g * 16) ^ ((row & 7) << 4)));
      *(u32x4*)(Yb + (size_t)(base + row) * 512 + g * 8) = v;
    }
  }
}

// ---------------------------------------------------------------------------
// K8: head bf16 MFMA GEMM. M=8192, N=256, K=512. A[tok] = Yb[p1]+Yb[p2].
// 128x128 tile (grid 64x2), 256 thr / 4 waves, wave tile 64x64.
// ---------------------------------------------------------------------------
__global__ __launch_bounds__(256) void k_head(const unsigned short* __restrict__ Yb,
                                              const int* __restrict__ tokpos,
                                              const unsigned short* __restrict__ headPk,
                                              const float* __restrict__ headB,
                                              float* __restrict__ out) {
  __shared__ __align__(16) char As[16384];  // [128 rows][64 k] bf16 swizzled
  __shared__ int tp[256];
  int tid = threadIdx.x;
  int w = tid >> 6, l = tid & 63;
  int l31 = l & 31, hi = l >> 5;
  int mg = w & 1, ng = w >> 1;
  int bm = blockIdx.x * 128, by = blockIdx.y;
  tp[tid] = tokpos[bm * 2 + tid];
  f32x16 acc00, acc01, acc10, acc11;
#pragma unroll
  for (int i = 0; i < 16; ++i) { acc00[i] = 0.f; acc01[i] = 0.f; acc10[i] = 0.f; acc11[i] = 0.f; }
  int nblk0 = by * 4 + ng * 2;
  __syncthreads();
  for (int kb = 0; kb < 8; ++kb) {
#pragma unroll
    for (int s = 0; s < 4; ++s) {
      int i = tid + s * 256;
      int row = i >> 3, g = i & 7;
      int p1 = tp[row * 2], p2 = tp[row * 2 + 1];
      u32x4 va = *(const u32x4*)(Yb + (size_t)p1 * 512 + kb * 64 + g * 8);
      u32x4 vb = *(const u32x4*)(Yb + (size_t)p2 * 512 + kb * 64 + g * 8);
      u32x4 o;
      o.x = (unsigned)f2bf(bflo(va.x) + bflo(vb.x)) | ((unsigned)f2bf(bfhi(va.x) + bfhi(vb.x)) << 16);
      o.y = (unsigned)f2bf(bflo(va.y) + bflo(vb.y)) | ((unsigned)f2bf(bfhi(va.y) + bfhi(vb.y)) << 16);
      o.z = (unsigned)f2bf(bflo(va.z) + bflo(vb.z)) | ((unsigned)f2bf(bfhi(va.z) + bfhi(vb.z)) << 16);
      o.w = (unsigned)f2bf(bflo(va.w) + bflo(vb.w)) | ((unsigned)f2bf(bfhi(va.w) + bfhi(vb.w)) << 16);
      *(u32x4*)(As + row * 128 + ((g * 16) ^ ((row & 7) << 4))) = o;
    }
    __syncthreads();
#pragma unroll
    for (int ks = 0; ks < 4; ++ks) {
      int r0 = mg * 64 + l31, r1 = r0 + 32;
      int kbyte = ks * 32 + hi * 16;
      bf16x8 a0 = ld_frag(As + r0 * 128 + (kbyte ^ ((r0 & 7) << 4)));
      bf16x8 a1 = ld_frag(As + r1 * 128 + (kbyte ^ ((r1 & 7) << 4)));
      const unsigned short* hp = headPk + ((size_t)nblk0 * 32 + kb * 4 + ks) * 512 + l * 8;
      bf16x8 b0 = *(const bf16x8*)hp;
      bf16x8 b1 = *(const bf16x8*)(hp + 32 * 512);
      acc00 = __builtin_amdgcn_mfma_f32_32x32x16_bf16(a0, b0, acc00, 0, 0, 0);
      acc01 = __builtin_amdgcn_mfma_f32_32x32x16_bf16(a0, b1, acc01, 0, 0, 0);
      acc10 = __builtin_amdgcn_mfma_f32_32x32x16_bf16(a1, b0, acc10, 0, 0, 0);
      acc11 = __builtin_amdgcn_mfma_f32_32x32x16_bf16(a1, b1, acc11, 0, 0, 0);
    }
    __syncthreads();
  }
  // epilogue: D col = n (lane), rows m; +bias; coalesced f32 stores
#pragma unroll
  for (int mf = 0; mf < 2; ++mf) {
#pragma unroll
    for (int nf = 0; nf < 2; ++nf) {
      int nc = by * 128 + ng * 64 + nf * 32 + l31;
      float hb = headB[nc];
#pragma unroll
      for (int r = 0; r < 16; ++r) {
        int m = bm + mg * 64 + mf * 32 + (r & 3) + 8 * (r >> 2) + 4 * hi;
        float v;
        if (mf == 0) v = (nf == 0) ? acc00[r] : acc01[r];
        else         v = (nf == 0) ? acc10[r] : acc11[r];
        out[(size_t)m * 256 + nc] = v + hb;
      }
    }
  }
}

extern "C" void kernel_launch(void* const* d_in, const int* in_sizes, int n_in,
                              void* d_out, int out_size, void* d_ws, size_t ws_size,
                              hipStream_t stream) {
  (void)in_sizes; (void)n_in; (void)out_size; (void)ws_size;
  const int* seq     = (const int*)d_in[0];
  const float* emb   = (const float*)d_in[1];
  const float* phi_w = (const float*)d_in[2];
  const float* phi_b = (const float*)d_in[3];
  const float* amp_w = (const float*)d_in[4];
  const float* amp_b = (const float*)d_in[5];
  const float* gate_w = (const float*)d_in[6];
  const float* gate_b = (const float*)d_in[7];
  const float* w1 = (const float*)d_in[8];
  const float* b1 = (const float*)d_in[9];
  const float* w2 = (const float*)d_in[10];
  const float* b2 = (const float*)d_in[11];
  const float* head_w = (const float*)d_in[12];
  const float* head_b = (const float*)d_in[13];
  float* out = (float*)d_out;

  char* ws = (char*)d_ws;
  const size_t BUF = 16777216;
  float* X    = (float*)(ws);                         // X -> xmoe (in place)
  float* COSb = (float*)(ws + BUF);                   // cos -> Yb (bf16)
  float* SINb = (float*)(ws + 2 * BUF);               // sin -> W1Pk (bf16)
  float* SIGb = (float*)(ws + 3 * BUF);               // sig -> W2Pk (bf16)
  unsigned short* Yb   = (unsigned short*)COSb;
  unsigned short* W1Pk = (unsigned short*)SINb;
  unsigned short* W2Pk = (unsigned short*)SIGb;
  char* sm = ws + 4 * BUF;
  int*      e01p   = (int*)(sm);                      // 32KB
  unsigned* w01p   = (unsigned*)(sm + 32768);         // 32KB
  int*      list   = (int*)(sm + 65536);              // 64KB
  float*    wlist  = (float*)(sm + 131072);           // 64KB
  int*      tokpos = (int*)(sm + 196608);             // 64KB
  int*      counts = (int*)(sm + 262144);
  int*      eoff   = (int*)(sm + 262144 + 64);
  unsigned short* headPk = (unsigned short*)(sm + 266240);  // 256KB

  k_embed<<<4096, 256, 0, stream>>>(seq, emb, X);
  // pack head_w [512][256] -> 8 nblk frags
  k_pack_b<<<dim3(8, 1, 1), 256, 0, stream>>>(head_w, 256, 0, headPk, 0, 32);
  // fused phi+amp fp32 GEMM
  k_phi<<<dim3(64, 8), 256, 0, stream>>>(X, phi_w, phi_b, amp_w, amp_b, COSb, SINb, SIGb);
  k_scan<<<32, 64, 0, stream>>>(COSb, SINb, SIGb, X, out + 2097152);
  // pack w1 [e][512][2048], w2 [e][2048][512] (after scan frees SINb/SIGb)
  k_pack_b<<<dim3(64, 1, 8), 256, 0, stream>>>(w1, 2048, (size_t)512 * 2048, W1Pk,
                                               (size_t)64 * 32 * 512, 32);
  k_pack_b<<<dim3(16, 4, 8), 256, 0, stream>>>(w2, 512, (size_t)2048 * 512, W2Pk,
                                               (size_t)16 * 128 * 512, 128);
  k_gate<<<256, 256, 0, stream>>>(X, gate_w, gate_b, e01p, w01p);
  k_build<<<1, 256, 0, stream>>>(e01p, w01p, list, wlist, counts, eoff, tokpos);
  // full coverage: counts[e] <= 8192 always (top-2 experts distinct per token)
  k_ffn<<<dim3(128, 8), 512, 0, stream>>>(X, list, wlist, counts, eoff,
                                          W1Pk, b1, W2Pk, b2, Yb);
  k_head<<<dim3(64, 2), 256, 0, stream>>>(Yb, tokpos, headPk, head_b, out);
}